// Round 10
// baseline (30.148 us; speedup 1.0000x reference)
//
#include <hip/hip_runtime.h>

// PolyAttn collapse: a = s^4/|s^4| == 1.0 identically, so
//   out[b,n,:] = vsum[b,:] @ w_o  (independent of n, q, k, alpha),
//   vsum[b,:]  = (sum_n x[b,n,:]) @ w_qkv[:, 2H:3H].
// R10 = R9 with the nontemporal-store compile fix (clang ext_vector_type;
// HIP_vector_type float4* is rejected by __builtin_nontemporal_store).
// 3 nodes; grid barriers ~15us / spin-waits ~100us on 8-XCD -> banned;
// atomic contention measured free (R8). kC: 2048 blocks x 4 rows, NT stores.

#define B_ 4
#define N_ 2048
#define D_ 1024
#define H_ 1024
#define H3_ 3072

typedef float fx4 __attribute__((ext_vector_type(4)));

// padded LDS xsum: d -> d + (d>>4); per-b stride 1088 floats.
#define XS(b, d) s_xs[(b) * 1088 + (d) + ((d) >> 4)]

// ws layout (floats): part[4][16][1024] (256 KB) | orow[4][1024]

// ---- kA: 1024 work blocks (b, ng, dq) + 4 blocks zeroing orow --------------
__global__ __launch_bounds__(256) void kA(const float* __restrict__ x,
                                          float4* __restrict__ part4,
                                          float4* __restrict__ orow4) {
    const int blk = blockIdx.x;
    const int t   = threadIdx.x;
    __shared__ float4 s4[16][16];
    if (blk < 1024) {
        const int b  = blk >> 8;           // 4
        const int ng = (blk >> 4) & 15;    // 16 groups of 128 rows
        const int dq = blk & 15;           // 16 slices of 64 floats
        const int d4 = t & 15;
        const int rr = t >> 4;             // 16 row streams x 8 rows
        const float4* x4 = reinterpret_cast<const float4*>(x);
        size_t base = ((size_t)b * N_ + ng * 128 + rr * 8) * (D_ / 4) + dq * 16 + d4;
        float4 acc = make_float4(0.f, 0.f, 0.f, 0.f);
#pragma unroll 8
        for (int i = 0; i < 8; ++i) {
            float4 v = x4[base + (size_t)i * (D_ / 4)];
            acc.x += v.x; acc.y += v.y; acc.z += v.z; acc.w += v.w;
        }
        s4[rr][d4] = acc;
        __syncthreads();
        if (t < 16) {
            float4 a = s4[0][t];
#pragma unroll 15
            for (int r = 1; r < 16; ++r) {
                float4 v = s4[r][t];
                a.x += v.x; a.y += v.y; a.z += v.z; a.w += v.w;
            }
            part4[((size_t)(b * 16 + ng)) * 256 + dq * 16 + t] = a;
        }
    } else {
        orow4[(blk - 1024) * 256 + t] = make_float4(0.f, 0.f, 0.f, 0.f);
    }
}

// ---- kB: 64 blocks x 512 thr; block owns h-chunk [h0, h0+16) ---------------
__global__ __launch_bounds__(512) void kB(const float4* __restrict__ part4,
                                          const float* __restrict__ w_qkv,
                                          const float* __restrict__ w_o,
                                          float* __restrict__ orow) {
    const int tid = threadIdx.x;
    const int h0  = blockIdx.x * 16;
    __shared__ float s_xs[4 * 1088 + 4];   // padded xsum, 17.4 KB
    __shared__ float s_red[64 * 33];       // [(b*16+h)][dg], stride-33 pad
    __shared__ float s_vs[64];             // [b*16+h]

    // step 1: xsum[b][d] = sum_ng part[b][ng][d]   (256 KB, L2-served)
#pragma unroll
    for (int k = 0; k < 2; ++k) {
        const int task = tid + k * 512;    // (b, d4)
        const int b = task >> 8, d4 = task & 255;
        const float4* p = part4 + (size_t)b * 16 * 256 + d4;
        float4 acc = make_float4(0.f, 0.f, 0.f, 0.f);
#pragma unroll
        for (int g = 0; g < 16; ++g) {
            float4 v = p[(size_t)g * 256];
            acc.x += v.x; acc.y += v.y; acc.z += v.z; acc.w += v.w;
        }
        const int d = d4 * 4;
        XS(b, d + 0) = acc.x;
        XS(b, d + 1) = acc.y;
        XS(b, d + 2) = acc.z;
        XS(b, d + 3) = acc.w;
    }
    __syncthreads();

    // step 2: vs[b][h] = sum_d xsum[b][d] * Wv[d, h0+h];  512 = 32 dg x 16 h
    {
        const int h  = tid & 15;
        const int dg = tid >> 4;
        const float* wv = w_qkv + 2 * H_ + h0 + h;
        float a0 = 0.f, a1 = 0.f, a2 = 0.f, a3 = 0.f;
#pragma unroll 4
        for (int i = 0; i < 32; ++i) {
            const int d = dg * 32 + i;
            const float w = wv[(size_t)d * H3_];
            a0 += XS(0, d) * w;
            a1 += XS(1, d) * w;
            a2 += XS(2, d) * w;
            a3 += XS(3, d) * w;
        }
        s_red[(0 * 16 + h) * 33 + dg] = a0;
        s_red[(1 * 16 + h) * 33 + dg] = a1;
        s_red[(2 * 16 + h) * 33 + dg] = a2;
        s_red[(3 * 16 + h) * 33 + dg] = a3;
    }
    __syncthreads();
    if (tid < 64) {                        // (b,h): fold 32 dg
        float v = 0.f;
#pragma unroll
        for (int k = 0; k < 32; ++k) v += s_red[tid * 33 + k];
        s_vs[tid] = v;
    }
    __syncthreads();

    // step 3: orow[b][d] += sum_j vs[b][j] * Wo[h0+j][d]   (coalesced in d)
#pragma unroll
    for (int k = 0; k < 8; ++k) {
        const int idx = tid + k * 512;     // (b, d) over 4096
        const int b = idx >> 10, d = idx & 1023;
        float o = 0.f;
#pragma unroll
        for (int j = 0; j < 16; ++j)
            o += s_vs[b * 16 + j] * w_o[(size_t)(h0 + j) * D_ + d];
        atomicAdd(&orow[idx], o);
    }
}

// ---- kC: 2048 blocks x 256 thr; block writes 4 contiguous rows (NT) --------
__global__ __launch_bounds__(256) void kC(const float* __restrict__ orow,
                                          float* __restrict__ out) {
    const int blk = blockIdx.x;
    const int b   = blk >> 9;              // 512 blocks per batch
    const int r0  = (blk & 511) * 4;       // 4 rows each
    const int t   = threadIdx.x;
    fx4 val = *reinterpret_cast<const fx4*>(orow + b * D_ + t * 4);
    fx4* out4 = reinterpret_cast<fx4*>(out);
    size_t base = ((size_t)b * N_ + r0) * (D_ / 4) + t;
#pragma unroll
    for (int i = 0; i < 4; ++i)
        __builtin_nontemporal_store(val, &out4[base + (size_t)i * (D_ / 4)]);
}

extern "C" void kernel_launch(void* const* d_in, const int* in_sizes, int n_in,
                              void* d_out, int out_size, void* d_ws, size_t ws_size,
                              hipStream_t stream) {
    const float* x     = (const float*)d_in[0];   // [B, N, D]
    const float* w_qkv = (const float*)d_in[1];   // [D, 3H]
    const float* w_o   = (const float*)d_in[2];   // [H, D]
    // d_in[3] = alpha — provably unused (a == 1 regardless of alpha).
    float* out = (float*)d_out;                   // [B, N, D] fp32

    float* part = (float*)d_ws;                   // 4*16*1024 = 65536 floats
    float* orow = part + (size_t)B_ * 16 * D_;    // 4096 floats

    kA<<<1028, 256, 0, stream>>>(x, (float4*)part, (float4*)orow);
    kB<<<64, 512, 0, stream>>>((const float4*)part, w_qkv, w_o, orow);
    kC<<<2048, 256, 0, stream>>>(orow, out);
}